// Round 1
// baseline (291.600 us; speedup 1.0000x reference)
//
#include <hip/hip_runtime.h>

// VecANDTree: x (65536,1024) f32 in {0,1}; out[row] = AND of all 1024 bits.
// (1024 = 2^10 so the reference's odd-carry path never triggers; threshold
// a+b>1.5 on {0,1} == logical AND.)
//
// R3 strategy: the prior kernel's 292 us is consistent with the TIMED input
// passing the 16-bit prefix on every row (poisoned buffer > 0.5), which sent
// every row through a serial 16x(64-lane-load -> ballot -> branch) chain:
// latency-bound, ~0.9 TB/s effective. This version keeps the 64 B/row probe
// (still optimal for random-bit data) but makes the full scan BW-optimal:
//   - wave-uniform 32-bit pass mask from the probe ballots
//   - per passing row: 4 coalesced float4 loads (1 KiB/instr, row in 4 loads)
//   - 2-row software pipeline: next row's loads issue before current row's
//     ballot, so each wave keeps >=4 KiB in flight (compiler emits
//     s_waitcnt vmcnt(4), leaving the prefetch loads outstanding).
// All-pass case: 2048 waves x 4-8 KiB in flight ~ 8-16 MiB >> BW*latency
// (~2.4 MiB) -> HBM-bound ~256 MiB / 6.3 TB/s ~ 41 us floor.

#define COLS 1024
#define ROWS_PER_WAVE 32
#define LOADS_PER_WAVE (ROWS_PER_WAVE / 4)   // 8 probe loads, 4 rows each
#define THREADS 256
#define WAVES_PER_BLOCK (THREADS / 64)

__global__ __launch_bounds__(THREADS) void VecANDTree_43860206027289_kernel(
    const float* __restrict__ x, float* __restrict__ out, int rows) {
    const int lane = threadIdx.x & 63;
    const int wave = blockIdx.x * WAVES_PER_BLOCK + (threadIdx.x >> 6);
    const int base = wave * ROWS_PER_WAVE;
    if (base >= rows) return;

    // ---- Phase A: 64 B/row prefix probe, 8 independent loads (4 rows x 16
    // lanes each), back-to-back for ILP. ----
    const int sub = lane >> 4;                       // which of 4 rows in a load
    const int col = lane & 15;                       // prefix column 0..15
    const float* bp = x + (size_t)base * COLS + (size_t)sub * COLS + col;

    float v[LOADS_PER_WAVE];
#pragma unroll
    for (int l = 0; l < LOADS_PER_WAVE; ++l) {
        v[l] = bp[(size_t)l * 4 * COLS];
    }

    // Wave-uniform pass mask: bit r set iff row base+r survived the probe.
    unsigned pmask = 0u;
#pragma unroll
    for (int l = 0; l < LOADS_PER_WAVE; ++l) {
        const unsigned long long m = __ballot(v[l] > 0.5f);
#pragma unroll
        for (int g = 0; g < 4; ++g) {
            if (((m >> (16 * g)) & 0xFFFFull) == 0xFFFFull)
                pmask |= 1u << (4 * l + g);
        }
    }

    float res = 0.0f;  // per-lane: lane r holds result of row base+r (r<32)

    // ---- Phase B: exact full scan of passing rows, BW-optimal.
    // Row r as float4: index r*256 + j*64 + lane, j=0..3 (each instr = a
    // coalesced contiguous 1 KiB). 2-row software pipeline. pmask is
    // wave-uniform, so all control flow below is non-divergent. ----
    if (pmask) {
        const float4* rowbase = (const float4*)(x + (size_t)base * COLS);
        unsigned pm = pmask;

        int rc = (int)__builtin_ctz(pm); pm &= pm - 1u;
        float4 a0, a1, a2, a3;
        {
            const float4* rp = rowbase + (size_t)rc * (COLS / 4);
            a0 = rp[lane]; a1 = rp[64 + lane]; a2 = rp[128 + lane]; a3 = rp[192 + lane];
        }
        while (true) {
            int rn = -1;
            float4 b0, b1, b2, b3;
            if (pm) {   // uniform: prefetch next passing row before resolving rc
                rn = (int)__builtin_ctz(pm); pm &= pm - 1u;
                const float4* rp = rowbase + (size_t)rn * (COLS / 4);
                b0 = rp[lane]; b1 = rp[64 + lane]; b2 = rp[128 + lane]; b3 = rp[192 + lane];
            }
            const bool ok =
                a0.x > 0.5f && a0.y > 0.5f && a0.z > 0.5f && a0.w > 0.5f &&
                a1.x > 0.5f && a1.y > 0.5f && a1.z > 0.5f && a1.w > 0.5f &&
                a2.x > 0.5f && a2.y > 0.5f && a2.z > 0.5f && a2.w > 0.5f &&
                a3.x > 0.5f && a3.y > 0.5f && a3.z > 0.5f && a3.w > 0.5f;
            const float r = __all(ok) ? 1.0f : 0.0f;
            if (lane == rc) res = r;
            if (rn < 0) break;
            rc = rn;
            a0 = b0; a1 = b1; a2 = b2; a3 = b3;
        }
    }

    // One coalesced 128 B store per wave.
    if (lane < ROWS_PER_WAVE) out[base + lane] = res;
}

extern "C" void kernel_launch(void* const* d_in, const int* in_sizes, int n_in,
                              void* d_out, int out_size, void* d_ws, size_t ws_size,
                              hipStream_t stream) {
    const float* x = (const float*)d_in[0];
    float* out = (float*)d_out;
    const int rows = out_size;                                    // 65536
    const int waves = (rows + ROWS_PER_WAVE - 1) / ROWS_PER_WAVE; // 2048
    const int blocks = (waves + WAVES_PER_BLOCK - 1) / WAVES_PER_BLOCK; // 512
    VecANDTree_43860206027289_kernel<<<blocks, THREADS, 0, stream>>>(x, out, rows);
}

// Round 2
// 291.141 us; speedup vs baseline: 1.0016x; 1.0016x over previous
//
#include <hip/hip_runtime.h>

// VecANDTree: x (65536,1024) f32 in {0,1}; out[row] = AND of all 1024 bits.
// (1024 = 2^10: the reference's odd-carry path never triggers; a+b>1.5 on
// {0,1} == logical AND.)
//
// R4: discriminator round. R3's full scan rewrite moved dur_us by -0.6us
// (noise) and the profile shows our kernel is NOT in the top-5 (all are
// 160-166us harness fills at 81-83% HBM peak) => kernel < 160us and dur_us
// is dominated by harness reset traffic. This version minimizes the probe
// path (the only part exercised by real random-bit data):
//   - ONE float4 load per wave probes 16 rows (4 lanes x 16 B = 64 B/row,
//     one full cache line per row, 100% of fetched bytes used)
//   - 4096 waves (1024 blocks x 256 thr) = 4 waves/SIMD for latency hiding
//   - pass mask via m & m>>1 & m>>2 & m>>3 (one ballot, 3 ANDs)
//   - rare full scan (P=2^-16/row) stays BW-optimal: 4x coalesced float4
//     loads/row, 2-row software pipeline, wave-uniform control flow.
// If dur_us stays ~291.6, the measurement is confirmed harness-floored.

#define COLS 1024
#define ROWS_PER_WAVE 16
#define THREADS 256
#define WAVES_PER_BLOCK (THREADS / 64)

__global__ __launch_bounds__(THREADS) void VecANDTree_43860206027289_kernel(
    const float* __restrict__ x, float* __restrict__ out, int rows) {
    const int lane = threadIdx.x & 63;
    const int wave = blockIdx.x * WAVES_PER_BLOCK + (threadIdx.x >> 6);
    const int base = wave * ROWS_PER_WAVE;
    if (base >= rows) return;

    const float4* xv = (const float4*)x;

    // ---- Phase A: prefix probe. lane covers row base+(lane>>2), bytes
    // (lane&3)*16 .. +15 of that row. One 1 KiB coalesced load per wave. ----
    int prow = base + (lane >> 2);
    if (prow >= rows) prow = rows - 1;               // tail guard (no-op at 65536)
    const float4 p = xv[(size_t)prow * (COLS / 4) + (lane & 3)];
    const bool ok = p.x > 0.5f && p.y > 0.5f && p.z > 0.5f && p.w > 0.5f;
    const unsigned long long m = __ballot(ok);

    // Row r (0..15) survives iff its 4-bit lane group is all-ones.
    // t has bit 4r set iff row r survived; wave-uniform.
    unsigned long long t = m & (m >> 1) & (m >> 2) & (m >> 3) &
                           0x1111111111111111ull;

    float res = 0.0f;  // lane r (<16) holds result for row base+r

    // ---- Phase B: exact full scan of surviving rows (rare on random data).
    // Row as 4 coalesced float4 loads (1 KiB each); 2-row pipeline so the
    // next row's loads are outstanding while the current row resolves.
    // All control flow wave-uniform (t is uniform). ----
    if (t) {
        const float4* rowbase = xv + (size_t)base * (COLS / 4);
        int rc = (int)(__builtin_ctzll(t) >> 2); t &= t - 1;
        float4 a0, a1, a2, a3;
        {
            const float4* rp = rowbase + (size_t)rc * (COLS / 4);
            a0 = rp[lane]; a1 = rp[64 + lane]; a2 = rp[128 + lane]; a3 = rp[192 + lane];
        }
        while (true) {
            int rn = -1;
            float4 b0, b1, b2, b3;
            if (t) {   // uniform: prefetch next surviving row before resolving rc
                rn = (int)(__builtin_ctzll(t) >> 2); t &= t - 1;
                const float4* rp = rowbase + (size_t)rn * (COLS / 4);
                b0 = rp[lane]; b1 = rp[64 + lane]; b2 = rp[128 + lane]; b3 = rp[192 + lane];
            }
            const bool okr =
                a0.x > 0.5f && a0.y > 0.5f && a0.z > 0.5f && a0.w > 0.5f &&
                a1.x > 0.5f && a1.y > 0.5f && a1.z > 0.5f && a1.w > 0.5f &&
                a2.x > 0.5f && a2.y > 0.5f && a2.z > 0.5f && a2.w > 0.5f &&
                a3.x > 0.5f && a3.y > 0.5f && a3.z > 0.5f && a3.w > 0.5f;
            const float r = __all(okr) ? 1.0f : 0.0f;
            if (lane == rc) res = r;
            if (rn < 0) break;
            rc = rn;
            a0 = b0; a1 = b1; a2 = b2; a3 = b3;
        }
    }

    // One coalesced 64 B store per wave.
    if (lane < ROWS_PER_WAVE && base + lane < rows) out[base + lane] = res;
}

extern "C" void kernel_launch(void* const* d_in, const int* in_sizes, int n_in,
                              void* d_out, int out_size, void* d_ws, size_t ws_size,
                              hipStream_t stream) {
    const float* x = (const float*)d_in[0];
    float* out = (float*)d_out;
    const int rows = out_size;                                        // 65536
    const int waves = (rows + ROWS_PER_WAVE - 1) / ROWS_PER_WAVE;     // 4096
    const int blocks = (waves + WAVES_PER_BLOCK - 1) / WAVES_PER_BLOCK; // 1024
    VecANDTree_43860206027289_kernel<<<blocks, THREADS, 0, stream>>>(x, out, rows);
}